// Round 4
// baseline (567.650 us; speedup 1.0000x reference)
//
#include <hip/hip_runtime.h>
#include <math.h>

// Problem constants
#define B_   4
#define C_   256
#define H_   200
#define W_   320
#define HW   (H_ * W_)        // 64000
#define BHW  (B_ * HW)        // 256000

// Tiling
#define TH   50               // output tile rows   (200 = 4*50)
#define TW   64               // output tile cols   (320 = 5*64)
#define PR   58               // staged rows = TH + 8
#define HSTR 68               // hmax LDS row stride (floats)
#define CS   16               // channel groups
#define CPG  (C_ / CS)        // 16 channels per group
#define NT   512              // threads per block
#define HBUF (PR * HSTR)      // 3944 floats

static_assert(TH * 4 == H_, "H tiling");
static_assert(TW * 5 == W_, "W tiling");

__device__ __forceinline__ float max3f(float a, float b, float c) {
  return fmaxf(fmaxf(a, b), c);   // clang folds to v_max3_f32
}

#define LD4(p, o) (*reinterpret_cast<const float4*>((p) + (o)))

__global__ __launch_bounds__(NT, 8) void hdm_main(const float* __restrict__ x,
                                                  float* __restrict__ wsM,
                                                  float* __restrict__ wsP) {
  // double-buffered hmax only: 31552 B -> 4 blocks/CU at VGPR<=64
  __shared__ float hmax[2 * HBUF];

  const int tile = blockIdx.x;          // 0..19
  const int b    = blockIdx.y;          // 0..3
  const int cg   = blockIdx.z;          // 0..CS-1
  const int th = tile / 5, tw = tile % 5;
  const int h0 = th * TH, w0 = tw * TW;
  const int tid = (int)threadIdx.x;

  const float* xg = x + (size_t)(b * C_ + cg * CPG) * HW;

  // ---- phase-1 (load + horizontal win9): run = r*8+s, 464 runs
  const bool act1 = tid < PR * 8;       // 464
  const int  r1   = tid >> 3, s1 = tid & 7;
  const int  gh   = h0 - 4 + r1;
  const bool rok  = (gh >= 0) && (gh < H_);
  const int  gw   = w0 - 4 + s1 * 8;
  const bool lft  = (gw < 0), rgt = (gw + 16 > W_);
  const int  gwc  = lft ? 0 : (rgt ? (W_ - 16) : gw);
  const int  ghc  = min(max(gh, 0), H_ - 1);
  const float* p1 = xg + (size_t)ghc * W_ + gwc;

  const bool edgeW = (tw == 0) || (tw == 4);   // block-uniform
  const bool edgeH = (th == 0) || (th == 3);   // block-uniform

  // ---- phase-2 (vertical win9 + accumulate): 448 runs = 7 rsegs x 64 cols
  const int  rs2  = tid >> 6, cw2 = tid & 63;
  const bool act2 = rs2 < 7;
  const int  r02  = rs2 * 8;
  const int  kv   = (rs2 == 6) ? 2 : 8;
  const float* p2 = xg + (size_t)h0 * W_ + (w0 + cw2);   // center-x base (global)

  float accM[8], accP[8];
#pragma unroll
  for (int i = 0; i < 8; ++i) { accM[i] = -INFINITY; accP[i] = 0.f; }

  // ---- prologue prefetch (channel 0)
  float4 A0, A1, A2, A3;
  if (act1) { A0 = LD4(p1, 0); A1 = LD4(p1, 4); A2 = LD4(p1, 8); A3 = LD4(p1, 12); }

  for (int cc = 0; cc < CPG; ++cc) {
    // ---- horizontal win9 directly on prefetched regs
    float wF[8];
    {
      const float t[16] = {A0.x, A0.y, A0.z, A0.w, A1.x, A1.y, A1.z, A1.w,
                           A2.x, A2.y, A2.z, A2.w, A3.x, A3.y, A3.z, A3.w};
      float m3[14];
#pragma unroll
      for (int i = 0; i < 14; ++i) m3[i] = max3f(t[i], t[i + 1], t[i + 2]);
      float w[8];
#pragma unroll
      for (int i = 0; i < 8; ++i) w[i] = max3f(m3[i], m3[i + 3], m3[i + 6]);
#pragma unroll
      for (int i = 0; i < 8; ++i) wF[i] = w[i];
      if (edgeW) {   // uniform branch; per-lane cndmask inside
        const float d0 = max3f(m3[0], m3[2], t[4]);     // prefix maxes (left edge)
        const float d1 = fmaxf(d0, t[5]);
        const float d2 = fmaxf(d1, t[6]);
        const float d3 = fmaxf(d2, t[7]);
        const float s8  = max3f(m3[8],  m3[11], m3[13]); // suffix maxes (right edge)
        const float s9  = max3f(m3[9],  m3[12], t[15]);
        const float s10 = fmaxf(m3[10], m3[13]);
        const float s11 = fmaxf(m3[11], m3[13]);
        wF[0] = lft ? d0 : (rgt ? w[4] : w[0]);
        wF[1] = lft ? d1 : (rgt ? w[5] : w[1]);
        wF[2] = lft ? d2 : (rgt ? w[6] : w[2]);
        wF[3] = lft ? d3 : (rgt ? w[7] : w[3]);
        wF[4] = lft ? w[0] : (rgt ? s8  : w[4]);
        wF[5] = lft ? w[1] : (rgt ? s9  : w[5]);
        wF[6] = lft ? w[2] : (rgt ? s10 : w[6]);
        wF[7] = lft ? w[3] : (rgt ? s11 : w[7]);
      }
      if (edgeH) {
#pragma unroll
        for (int i = 0; i < 8; ++i) wF[i] = rok ? wF[i] : -INFINITY;
      }
    }

    // ---- write hmax buf(cc&1)  (dbuf: no pre-barrier needed, see proof R3)
    float* hb = &hmax[(cc & 1) * HBUF];
    if (act1) {
      float* hr = hb + r1 * HSTR + s1 * 8;
      *reinterpret_cast<float4*>(hr + 0) = make_float4(wF[0], wF[1], wF[2], wF[3]);
      *reinterpret_cast<float4*>(hr + 4) = make_float4(wF[4], wF[5], wF[6], wF[7]);
    }

    __syncthreads();   // drains lgkm only (no fresh vmem before it)

    // ---- prefetch AFTER barrier: latency hides under vpass, not the barrier
    if (act1 && (cc + 1 < CPG)) {
      p1 += HW;
      A0 = LD4(p1, 0); A1 = LD4(p1, 4); A2 = LD4(p1, 8); A3 = LD4(p1, 12);
    }

    // ---- vertical win9 + streaming depth-max / prob accumulate
    if (act2) {
      const float* pc = p2 + (size_t)cc * HW;
      float xc[8];                        // center x from global (L1/L2 hit)
#pragma unroll
      for (int i = 0; i < 8; ++i) {
        const int ri = min(r02 + i, TH - 1);   // clamp only matters for rseg 6
        xc[i] = pc[(size_t)ri * W_];
      }
      float hv[16];
#pragma unroll
      for (int i = 0; i < 16; ++i) {
        const int r = min(r02 + i, PR - 1);
        hv[i] = hb[r * HSTR + cw2];
      }
      float m3v[14];
#pragma unroll
      for (int i = 0; i < 14; ++i) m3v[i] = max3f(hv[i], hv[i + 1], hv[i + 2]);
#pragma unroll
      for (int i = 0; i < 8; ++i) {
        const float w9  = max3f(m3v[i], m3v[i + 3], m3v[i + 6]);
        const float xc_ = xc[i];
        const float add = (xc_ == w9) ? xc_ : 0.f;
        const bool  gt  = xc_ > accM[i];
        const bool  eq  = xc_ == accM[i];
        accP[i] = gt ? add : (accP[i] + (eq ? add : 0.f));
        accM[i] = gt ? xc_ : accM[i];
      }
    }
  }

  // ---- write per-group partials
  if (act2) {
    const size_t obase = (size_t)cg * BHW + (size_t)b * HW;
#pragma unroll
    for (int i = 0; i < 8; ++i) {
      if (i < kv) {
        const size_t idx = obase + (size_t)(h0 + r02 + i) * W_ + (w0 + cw2);
        wsM[idx] = accM[i];
        wsP[idx] = accP[i];
      }
    }
  }
}

// exact tie-safe combine over channel groups
__global__ __launch_bounds__(256) void hdm_combine(const float* __restrict__ wsM,
                                                   const float* __restrict__ wsP,
                                                   float* __restrict__ out) {
  const int px = blockIdx.x * 256 + (int)threadIdx.x;
  if (px >= BHW) return;
  float gm = -INFINITY, p = 0.f;
#pragma unroll
  for (int cs = 0; cs < CS; ++cs) {
    const float m = wsM[(size_t)cs * BHW + px];
    const float q = wsP[(size_t)cs * BHW + px];
    const bool gt = m > gm;
    const bool eq = m == gm;
    p  = gt ? q : (p + (eq ? q : 0.f));
    gm = gt ? m : gm;
  }
  out[px] = p;
}

extern "C" void kernel_launch(void* const* d_in, const int* in_sizes, int n_in,
                              void* d_out, int out_size, void* d_ws, size_t ws_size,
                              hipStream_t stream) {
  const float* x = (const float*)d_in[0];
  float* wsM = (float*)d_ws;                       // CS*BHW floats
  float* wsP = wsM + (size_t)CS * BHW;             // CS*BHW floats (32.8 MB total)
  float* out = (float*)d_out;

  hipLaunchKernelGGL(hdm_main, dim3(20, B_, CS), dim3(NT), 0, stream, x, wsM, wsP);
  hipLaunchKernelGGL(hdm_combine, dim3((BHW + 255) / 256), dim3(256), 0, stream,
                     wsM, wsP, out);
}

// Round 5
// 378.003 us; speedup vs baseline: 1.5017x; 1.5017x over previous
//
#include <hip/hip_runtime.h>
#include <math.h>

// Problem constants
#define B_   4
#define C_   256
#define H_   200
#define W_   320
#define HW   (H_ * W_)        // 64000
#define BHW  (B_ * HW)        // 256000

// Tiling
#define TH   50               // output tile rows   (200 = 4*50)
#define TW   64               // output tile cols   (320 = 5*64)
#define PR   58               // staged rows = TH + 8
#define HSTR 68               // hmax LDS row stride (floats)
#define CS   16               // channel groups
#define CPG  (C_ / CS)        // 16 channels per group
#define NT   512              // threads per block
#define HBUF (PR * HSTR)      // 3944 floats

static_assert(TH * 4 == H_, "H tiling");
static_assert(TW * 5 == W_, "W tiling");

__device__ __forceinline__ float max3f(float a, float b, float c) {
  return fmaxf(fmaxf(a, b), c);   // clang folds to v_max3_f32
}

#define LD4(p, o) (*reinterpret_cast<const float4*>((p) + (o)))

// (512,4): R4's (512,8) forced VGPR=32 -> massive scratch spills (WRITE 142MB).
// 4 waves/EU min keeps allocator at <=128 VGPR; kernel needs ~64-96 live.
__global__ __launch_bounds__(NT, 4) void hdm_main(const float* __restrict__ x,
                                                  float* __restrict__ wsM,
                                                  float* __restrict__ wsP) {
  // double-buffered hmax only: 31552 B
  __shared__ float hmax[2 * HBUF];

  const int tile = blockIdx.x;          // 0..19
  const int b    = blockIdx.y;          // 0..3
  const int cg   = blockIdx.z;          // 0..CS-1
  const int th = tile / 5, tw = tile % 5;
  const int h0 = th * TH, w0 = tw * TW;
  const int tid = (int)threadIdx.x;

  const float* xg = x + (size_t)(b * C_ + cg * CPG) * HW;

  // ---- phase-1 (load + horizontal win9): run = r*8+s, 464 runs
  const bool act1 = tid < PR * 8;       // 464
  const int  r1   = tid >> 3, s1 = tid & 7;
  const int  gh   = h0 - 4 + r1;
  const bool rok  = (gh >= 0) && (gh < H_);
  const int  gw   = w0 - 4 + s1 * 8;
  const bool lft  = (gw < 0), rgt = (gw + 16 > W_);
  const int  gwc  = lft ? 0 : (rgt ? (W_ - 16) : gw);
  const int  ghc  = min(max(gh, 0), H_ - 1);
  const float* p1 = xg + (size_t)ghc * W_ + gwc;

  const bool edgeW = (tw == 0) || (tw == 4);   // block-uniform
  const bool edgeH = (th == 0) || (th == 3);   // block-uniform

  // ---- phase-2 (vertical win9 + accumulate): 448 runs = 7 rsegs x 64 cols
  const int  rs2  = tid >> 6, cw2 = tid & 63;
  const bool act2 = rs2 < 7;
  const int  r02  = rs2 * 8;
  const int  kv   = (rs2 == 6) ? 2 : 8;
  const float* p2 = xg + (size_t)h0 * W_ + (w0 + cw2);   // center-x base (global)

  float accM[8], accP[8];
#pragma unroll
  for (int i = 0; i < 8; ++i) { accM[i] = -INFINITY; accP[i] = 0.f; }

  // ---- prologue prefetch (channel 0)
  float4 A0, A1, A2, A3;
  if (act1) { A0 = LD4(p1, 0); A1 = LD4(p1, 4); A2 = LD4(p1, 8); A3 = LD4(p1, 12); }

  for (int cc = 0; cc < CPG; ++cc) {
    // ---- horizontal win9 directly on prefetched regs
    float wF[8];
    {
      const float t[16] = {A0.x, A0.y, A0.z, A0.w, A1.x, A1.y, A1.z, A1.w,
                           A2.x, A2.y, A2.z, A2.w, A3.x, A3.y, A3.z, A3.w};
      float m3[14];
#pragma unroll
      for (int i = 0; i < 14; ++i) m3[i] = max3f(t[i], t[i + 1], t[i + 2]);
      float w[8];
#pragma unroll
      for (int i = 0; i < 8; ++i) w[i] = max3f(m3[i], m3[i + 3], m3[i + 6]);
#pragma unroll
      for (int i = 0; i < 8; ++i) wF[i] = w[i];
      if (edgeW) {   // uniform branch; per-lane cndmask inside
        const float d0 = max3f(m3[0], m3[2], t[4]);     // prefix maxes (left edge)
        const float d1 = fmaxf(d0, t[5]);
        const float d2 = fmaxf(d1, t[6]);
        const float d3 = fmaxf(d2, t[7]);
        const float s8  = max3f(m3[8],  m3[11], m3[13]); // suffix maxes (right edge)
        const float s9  = max3f(m3[9],  m3[12], t[15]);
        const float s10 = fmaxf(m3[10], m3[13]);
        const float s11 = fmaxf(m3[11], m3[13]);
        wF[0] = lft ? d0 : (rgt ? w[4] : w[0]);
        wF[1] = lft ? d1 : (rgt ? w[5] : w[1]);
        wF[2] = lft ? d2 : (rgt ? w[6] : w[2]);
        wF[3] = lft ? d3 : (rgt ? w[7] : w[3]);
        wF[4] = lft ? w[0] : (rgt ? s8  : w[4]);
        wF[5] = lft ? w[1] : (rgt ? s9  : w[5]);
        wF[6] = lft ? w[2] : (rgt ? s10 : w[6]);
        wF[7] = lft ? w[3] : (rgt ? s11 : w[7]);
      }
      if (edgeH) {
#pragma unroll
        for (int i = 0; i < 8; ++i) wF[i] = rok ? wF[i] : -INFINITY;
      }
    }

    // ---- write hmax buf(cc&1)  (dbuf: no pre-barrier needed)
    float* hb = &hmax[(cc & 1) * HBUF];
    if (act1) {
      float* hr = hb + r1 * HSTR + s1 * 8;
      *reinterpret_cast<float4*>(hr + 0) = make_float4(wF[0], wF[1], wF[2], wF[3]);
      *reinterpret_cast<float4*>(hr + 4) = make_float4(wF[4], wF[5], wF[6], wF[7]);
    }

    __syncthreads();   // drains lgkm only (no fresh vmem before it)

    // ---- prefetch AFTER barrier: latency hides under vpass, not the barrier
    if (act1 && (cc + 1 < CPG)) {
      p1 += HW;
      A0 = LD4(p1, 0); A1 = LD4(p1, 4); A2 = LD4(p1, 8); A3 = LD4(p1, 12);
    }

    // ---- vertical win9 + streaming depth-max / prob accumulate
    if (act2) {
      const float* pc = p2 + (size_t)cc * HW;
      float xc[8];                        // center x from global (L1/L2 hit)
#pragma unroll
      for (int i = 0; i < 8; ++i) {
        const int ri = min(r02 + i, TH - 1);   // clamp only matters for rseg 6
        xc[i] = pc[(size_t)ri * W_];
      }
      float hv[16];
#pragma unroll
      for (int i = 0; i < 16; ++i) {
        const int r = min(r02 + i, PR - 1);
        hv[i] = hb[r * HSTR + cw2];
      }
      float m3v[14];
#pragma unroll
      for (int i = 0; i < 14; ++i) m3v[i] = max3f(hv[i], hv[i + 1], hv[i + 2]);
#pragma unroll
      for (int i = 0; i < 8; ++i) {
        const float w9  = max3f(m3v[i], m3v[i + 3], m3v[i + 6]);
        const float xc_ = xc[i];
        const float add = (xc_ == w9) ? xc_ : 0.f;
        const bool  gt  = xc_ > accM[i];
        const bool  eq  = xc_ == accM[i];
        accP[i] = gt ? add : (accP[i] + (eq ? add : 0.f));
        accM[i] = gt ? xc_ : accM[i];
      }
    }
  }

  // ---- write per-group partials
  if (act2) {
    const size_t obase = (size_t)cg * BHW + (size_t)b * HW;
#pragma unroll
    for (int i = 0; i < 8; ++i) {
      if (i < kv) {
        const size_t idx = obase + (size_t)(h0 + r02 + i) * W_ + (w0 + cw2);
        wsM[idx] = accM[i];
        wsP[idx] = accP[i];
      }
    }
  }
}

// exact tie-safe combine over channel groups
__global__ __launch_bounds__(256) void hdm_combine(const float* __restrict__ wsM,
                                                   const float* __restrict__ wsP,
                                                   float* __restrict__ out) {
  const int px = blockIdx.x * 256 + (int)threadIdx.x;
  if (px >= BHW) return;
  float gm = -INFINITY, p = 0.f;
#pragma unroll
  for (int cs = 0; cs < CS; ++cs) {
    const float m = wsM[(size_t)cs * BHW + px];
    const float q = wsP[(size_t)cs * BHW + px];
    const bool gt = m > gm;
    const bool eq = m == gm;
    p  = gt ? q : (p + (eq ? q : 0.f));
    gm = gt ? m : gm;
  }
  out[px] = p;
}

extern "C" void kernel_launch(void* const* d_in, const int* in_sizes, int n_in,
                              void* d_out, int out_size, void* d_ws, size_t ws_size,
                              hipStream_t stream) {
  const float* x = (const float*)d_in[0];
  float* wsM = (float*)d_ws;                       // CS*BHW floats
  float* wsP = wsM + (size_t)CS * BHW;             // CS*BHW floats (32.8 MB total)
  float* out = (float*)d_out;

  hipLaunchKernelGGL(hdm_main, dim3(20, B_, CS), dim3(NT), 0, stream, x, wsM, wsP);
  hipLaunchKernelGGL(hdm_combine, dim3((BHW + 255) / 256), dim3(256), 0, stream,
                     wsM, wsP, out);
}

// Round 6
// 369.142 us; speedup vs baseline: 1.5378x; 1.0240x over previous
//
#include <hip/hip_runtime.h>
#include <math.h>

// Problem constants
#define B_   4
#define C_   256
#define H_   200
#define W_   320
#define HW   (H_ * W_)        // 64000
#define BHW  (B_ * HW)        // 256000

// Tiling
#define TH   50               // output tile rows   (200 = 4*50)
#define TW   64               // output tile cols   (320 = 5*64)
#define PR   58               // staged rows = TH + 8
#define HSTR 68               // hmax LDS row stride (floats)
#define CS   16               // channel groups
#define CPG  (C_ / CS)        // 16 channels per group
#define NT   512              // threads per block
#define HBUF (PR * HSTR)      // 3944 floats

static_assert(TH * 4 == H_, "H tiling");
static_assert(TW * 5 == W_, "W tiling");
static_assert((CPG & 1) == 0, "parity dbuf needs even CPG");

__device__ __forceinline__ float max3f(float a, float b, float c) {
  return fmaxf(fmaxf(a, b), c);   // clang folds to v_max3_f32
}

#define LD4(p, o) (*reinterpret_cast<const float4*>((p) + (o)))

// (512,4): (512,8) forced VGPR=32 -> spills (R4). This kernel needs ~100 VGPR.
__global__ __launch_bounds__(NT, 4) void hdm_main(const float* __restrict__ x,
                                                  float* __restrict__ wsM,
                                                  float* __restrict__ wsP) {
  __shared__ float hmax[2 * HBUF];   // 31552 B, parity double-buffer

  const int tile = blockIdx.x;          // 0..19
  const int b    = blockIdx.y;          // 0..3
  const int cg   = blockIdx.z;          // 0..CS-1
  const int th = tile / 5, tw = tile % 5;
  const int h0 = th * TH, w0 = tw * TW;
  const int tid = (int)threadIdx.x;

  const float* xg = x + (size_t)(b * C_ + cg * CPG) * HW;

  // ---- phase-1 (load + horizontal win9): run = r*8+s, 464 runs
  const bool act1 = tid < PR * 8;       // 464
  const int  r1   = tid >> 3, s1 = tid & 7;
  const int  gh   = h0 - 4 + r1;
  const bool rok  = (gh >= 0) && (gh < H_);
  const int  gw   = w0 - 4 + s1 * 8;
  const bool lft  = (gw < 0), rgt = (gw + 16 > W_);
  const int  gwc  = lft ? 0 : (rgt ? (W_ - 16) : gw);
  const int  ghc  = min(max(gh, 0), H_ - 1);
  const float* p1 = xg + (size_t)ghc * W_ + gwc;

  const bool edgeW = (tw == 0) || (tw == 4);   // block-uniform
  const bool edgeH = (th == 0) || (th == 3);   // block-uniform

  // ---- phase-2 (vertical win9 + accumulate): 448 runs = 7 rsegs x 64 cols
  const int  rs2  = tid >> 6, cw2 = tid & 63;
  const bool act2 = rs2 < 7;
  const int  r02  = rs2 * 8;
  const int  kv   = (rs2 == 6) ? 2 : 8;
  const float* p2 = xg + (size_t)h0 * W_ + (w0 + cw2);   // center-x col base

  float accM[8], accP[8];
#pragma unroll
  for (int i = 0; i < 8; ++i) { accM[i] = -INFINITY; accP[i] = 0.f; }

  // ---- 2-deep prefetch buffers (parity-indexed; loop unrolled x2 so all
  //      indices are compile-time -> registers, no scratch)
  float4 Ab[2][4];
  float  Xb[2][8];
  if (act1) {
    Ab[0][0] = LD4(p1, 0); Ab[0][1] = LD4(p1, 4);
    Ab[0][2] = LD4(p1, 8); Ab[0][3] = LD4(p1, 12);
  }
  if (act2) {
#pragma unroll
    for (int i = 0; i < 8; ++i) Xb[0][i] = p2[(size_t)min(r02 + i, TH - 1) * W_];
  }
  if (act1) {
    const float* q = p1 + HW;
    Ab[1][0] = LD4(q, 0); Ab[1][1] = LD4(q, 4);
    Ab[1][2] = LD4(q, 8); Ab[1][3] = LD4(q, 12);
  }
  if (act2) {
    const float* q = p2 + HW;
#pragma unroll
    for (int i = 0; i < 8; ++i) Xb[1][i] = q[(size_t)min(r02 + i, TH - 1) * W_];
  }

#pragma unroll 2
  for (int cc = 0; cc < CPG; ++cc) {
    const int sl = cc & 1;

    // ---- horizontal win9 on A(cc) = Ab[sl]  (issued 2 channels ago)
    float wF[8];
    {
      const float4 A0 = Ab[sl][0], A1 = Ab[sl][1], A2 = Ab[sl][2], A3 = Ab[sl][3];
      const float t[16] = {A0.x, A0.y, A0.z, A0.w, A1.x, A1.y, A1.z, A1.w,
                           A2.x, A2.y, A2.z, A2.w, A3.x, A3.y, A3.z, A3.w};
      float m3[14];
#pragma unroll
      for (int i = 0; i < 14; ++i) m3[i] = max3f(t[i], t[i + 1], t[i + 2]);
      float w[8];
#pragma unroll
      for (int i = 0; i < 8; ++i) w[i] = max3f(m3[i], m3[i + 3], m3[i + 6]);
#pragma unroll
      for (int i = 0; i < 8; ++i) wF[i] = w[i];
      if (edgeW) {   // uniform branch; per-lane cndmask inside
        const float d0 = max3f(m3[0], m3[2], t[4]);     // prefix maxes (left)
        const float d1 = fmaxf(d0, t[5]);
        const float d2 = fmaxf(d1, t[6]);
        const float d3 = fmaxf(d2, t[7]);
        const float s8  = max3f(m3[8],  m3[11], m3[13]); // suffix maxes (right)
        const float s9  = max3f(m3[9],  m3[12], t[15]);
        const float s10 = fmaxf(m3[10], m3[13]);
        const float s11 = fmaxf(m3[11], m3[13]);
        wF[0] = lft ? d0 : (rgt ? w[4] : w[0]);
        wF[1] = lft ? d1 : (rgt ? w[5] : w[1]);
        wF[2] = lft ? d2 : (rgt ? w[6] : w[2]);
        wF[3] = lft ? d3 : (rgt ? w[7] : w[3]);
        wF[4] = lft ? w[0] : (rgt ? s8  : w[4]);
        wF[5] = lft ? w[1] : (rgt ? s9  : w[5]);
        wF[6] = lft ? w[2] : (rgt ? s10 : w[6]);
        wF[7] = lft ? w[3] : (rgt ? s11 : w[7]);
      }
      if (edgeH) {
#pragma unroll
        for (int i = 0; i < 8; ++i) wF[i] = rok ? wF[i] : -INFINITY;
      }
    }

    // ---- write hmax buf(sl)  (dbuf proof: reader of buf(sl)@cc finishes
    //      before barrier(cc+1); writer of buf(sl)@cc+2 is after it)
    float* hb = &hmax[sl * HBUF];
    if (act1) {
      float* hr = hb + r1 * HSTR + s1 * 8;
      *reinterpret_cast<float4*>(hr + 0) = make_float4(wF[0], wF[1], wF[2], wF[3]);
      *reinterpret_cast<float4*>(hr + 4) = make_float4(wF[4], wF[5], wF[6], wF[7]);
    }

    __syncthreads();

    // ---- snapshot X(cc) before its slot is re-targeted
    float xc[8];
#pragma unroll
    for (int i = 0; i < 8; ++i) xc[i] = Xb[sl][i];

    // ---- issue channel cc+2 into slot sl (slack: full iteration + vpass)
    if (cc + 2 < CPG) {
      if (act1) {
        const float* q = p1 + (size_t)(cc + 2) * HW;
        Ab[sl][0] = LD4(q, 0); Ab[sl][1] = LD4(q, 4);
        Ab[sl][2] = LD4(q, 8); Ab[sl][3] = LD4(q, 12);
      }
      if (act2) {
        const float* q = p2 + (size_t)(cc + 2) * HW;
#pragma unroll
        for (int i = 0; i < 8; ++i) Xb[sl][i] = q[(size_t)min(r02 + i, TH - 1) * W_];
      }
    }

    // ---- vertical win9 + streaming depth-max / prob accumulate
    if (act2) {
      float hv[16];
#pragma unroll
      for (int i = 0; i < 16; ++i) {
        const int r = min(r02 + i, PR - 1);   // clamp matters only for rseg 6
        hv[i] = hb[r * HSTR + cw2];
      }
      float m3v[14];
#pragma unroll
      for (int i = 0; i < 14; ++i) m3v[i] = max3f(hv[i], hv[i + 1], hv[i + 2]);
#pragma unroll
      for (int i = 0; i < 8; ++i) {
        const float w9  = max3f(m3v[i], m3v[i + 3], m3v[i + 6]);
        const float xc_ = xc[i];
        const float add = (xc_ == w9) ? xc_ : 0.f;
        const bool  gt  = xc_ > accM[i];
        const bool  eq  = xc_ == accM[i];
        accP[i] = gt ? add : (accP[i] + (eq ? add : 0.f));
        accM[i] = gt ? xc_ : accM[i];
      }
    }
  }

  // ---- write per-group partials
  if (act2) {
    const size_t obase = (size_t)cg * BHW + (size_t)b * HW;
#pragma unroll
    for (int i = 0; i < 8; ++i) {
      if (i < kv) {
        const size_t idx = obase + (size_t)(h0 + r02 + i) * W_ + (w0 + cw2);
        wsM[idx] = accM[i];
        wsP[idx] = accP[i];
      }
    }
  }
}

// exact tie-safe combine over channel groups
__global__ __launch_bounds__(256) void hdm_combine(const float* __restrict__ wsM,
                                                   const float* __restrict__ wsP,
                                                   float* __restrict__ out) {
  const int px = blockIdx.x * 256 + (int)threadIdx.x;
  if (px >= BHW) return;
  float gm = -INFINITY, p = 0.f;
#pragma unroll
  for (int cs = 0; cs < CS; ++cs) {
    const float m = wsM[(size_t)cs * BHW + px];
    const float q = wsP[(size_t)cs * BHW + px];
    const bool gt = m > gm;
    const bool eq = m == gm;
    p  = gt ? q : (p + (eq ? q : 0.f));
    gm = gt ? m : gm;
  }
  out[px] = p;
}

extern "C" void kernel_launch(void* const* d_in, const int* in_sizes, int n_in,
                              void* d_out, int out_size, void* d_ws, size_t ws_size,
                              hipStream_t stream) {
  const float* x = (const float*)d_in[0];
  float* wsM = (float*)d_ws;                       // CS*BHW floats
  float* wsP = wsM + (size_t)CS * BHW;             // CS*BHW floats (32.8 MB total)
  float* out = (float*)d_out;

  hipLaunchKernelGGL(hdm_main, dim3(20, B_, CS), dim3(NT), 0, stream, x, wsM, wsP);
  hipLaunchKernelGGL(hdm_combine, dim3((BHW + 255) / 256), dim3(256), 0, stream,
                     wsM, wsP, out);
}